// Round 8
// baseline (623.371 us; speedup 1.0000x reference)
//
#include <hip/hip_runtime.h>
#include <hip/hip_bf16.h>
#include <hip/hip_cooperative_groups.h>

namespace cg = cooperative_groups;

#define D 128
#define MAXB 512

typedef __attribute__((ext_vector_type(8))) short short8;
typedef __attribute__((ext_vector_type(4))) float float4v;
typedef __attribute__((ext_vector_type(2))) float float2v;

__device__ __forceinline__ float4v mfma16(short8 a, short8 b, float4v c) {
  return __builtin_amdgcn_mfma_f32_16x16x32_bf16(a, b, c, 0, 0, 0);
}
__device__ __forceinline__ float b2f(__hip_bfloat16 x) { return __bfloat162float(x); }
__device__ __forceinline__ __hip_bfloat16 f2b(float x) { return __float2bfloat16(x); }
__device__ __forceinline__ unsigned short f2b_bits(float x) {
  __hip_bfloat16 h = __float2bfloat16(x);
  return *reinterpret_cast<unsigned short*>(&h);
}

__device__ __forceinline__ float ldf(const float* p, size_t i) { return p[i]; }
__device__ __forceinline__ float ldf(const __hip_bfloat16* p, size_t i) { return b2f(p[i]); }
__device__ __forceinline__ void stf(float* p, size_t i, float v) { p[i] = v; }
__device__ __forceinline__ void stf(__hip_bfloat16* p, size_t i, float v) { p[i] = f2b(v); }

// relaxed workgroup barrier: drain LDS ops only, leave global loads in flight.
__device__ __forceinline__ void bar_lds() {
  asm volatile("s_waitcnt lgkmcnt(0)\n\ts_barrier" ::: "memory");
}

// packed bf16-pair -> float2 (lo, hi)
__device__ __forceinline__ float2v up2(unsigned w) {
  float2v r;
  r.x = __uint_as_float(w << 16);
  r.y = __uint_as_float(w & 0xffff0000u);
  return r;
}
// fp8 e4m3 (OCP on gfx950) encode/decode via the HW cvt pair — self-consistent.
__device__ __forceinline__ unsigned char f2fp8(float x) {
  int r = __builtin_amdgcn_cvt_pk_fp8_f32(x, x, 0, false);
  return (unsigned char)(r & 0xff);
}
__device__ __forceinline__ float2v cvt2lo(unsigned w) {
  return __builtin_amdgcn_cvt_pk_f32_fp8(w, false);
}
__device__ __forceinline__ float2v cvt2hi(unsigned w) {
  return __builtin_amdgcn_cvt_pk_f32_fp8(w, true);
}

__device__ __forceinline__ short8 cvt8(float4 u0, float4 u1) {
  short8 a;
  a[0] = (short)f2b_bits(u0.x); a[1] = (short)f2b_bits(u0.y);
  a[2] = (short)f2b_bits(u0.z); a[3] = (short)f2b_bits(u0.w);
  a[4] = (short)f2b_bits(u1.x); a[5] = (short)f2b_bits(u1.y);
  a[6] = (short)f2b_bits(u1.z); a[7] = (short)f2b_bits(u1.w);
  return a;
}

// ============= cooperative prep kernel: CSR build (binned) + weight cast ==========
// 512 blocks x 256 threads (2 blocks/CU, co-resident). Phases separated by grid.sync:
//  P0: zero bh        P1: bucket histogram + weight cast (independent, folded in)
//  P2: bucket scan (block 0)   P3: bin edges into bucket runs (packed 32-bit)
//  P4: per-bucket fine scatter -> deg/offs/csr
// frag layout for weights (KxNcol): out[((c*4+quad)*Ncol + col)*8 + j]
//   = W[(c*32 + quad*8 + j)*Ncol + col]  -> one aligned 16-B load per fragment.
__global__ __launch_bounds__(256) void k_prep(
    const int* __restrict__ src, const int* __restrict__ dst,
    int* __restrict__ bh, int* __restrict__ bbase, int* __restrict__ bcur,
    unsigned* __restrict__ binned, int* __restrict__ deg, int* __restrict__ offs,
    int* __restrict__ csr,
    const float* __restrict__ wq, const float* __restrict__ wk,
    const float* __restrict__ wv, const float* __restrict__ wo,
    const float* __restrict__ w1, const float* __restrict__ w2,
    __hip_bfloat16* __restrict__ oq, __hip_bfloat16* __restrict__ ok,
    __hip_bfloat16* __restrict__ ov, __hip_bfloat16* __restrict__ oo,
    __hip_bfloat16* __restrict__ o1, __hip_bfloat16* __restrict__ o2,
    int N, int E, int NBuck) {
  __shared__ int smem[1024];
  cg::grid_group grid = cg::this_grid();
  const int t = threadIdx.x, b = blockIdx.x;
  const int gthreads = gridDim.x * 256;
  const int gid = b * 256 + t;

  // ---- P0: zero bucket histogram ----
  for (int i = gid; i < MAXB; i += gthreads) bh[i] = 0;
  grid.sync();

  // ---- P1: bucket histogram (LDS-combined) + weight cast ----
  {
    for (int i = t; i < MAXB; i += 256) smem[i] = 0;
    __syncthreads();
    for (int e = gid; e < E; e += gthreads) atomicAdd(&smem[dst[e] >> 8], 1);
    __syncthreads();
    for (int i = t; i < MAXB; i += 256)
      if (smem[i]) atomicAdd(&bh[i], smem[i]);
  }
  {  // cast weights to fragment order (131072 elements, exactly one pass)
    int i = gid;
    if (i < 65536) {  // wq, wk, wv, wo : K=128, Ncol=128
      int m = i & 16383;
      int which = i >> 14;
      const float* s = (which == 0) ? wq : (which == 1) ? wk : (which == 2) ? wv : wo;
      __hip_bfloat16* o = (which == 0) ? oq : (which == 1) ? ok : (which == 2) ? ov : oo;
      int j = m & 7, t2 = m >> 3;
      int col = t2 & 127, cq = t2 >> 7;
      o[m] = f2b(s[((cq >> 2) * 32 + (cq & 3) * 8 + j) * 128 + col]);
    } else if (i < 98304) {  // w1 : K=128, Ncol=256
      int m = i - 65536;
      int j = m & 7, t2 = m >> 3;
      int col = t2 & 255, cq = t2 >> 8;
      o1[m] = f2b(w1[((cq >> 2) * 32 + (cq & 3) * 8 + j) * 256 + col]);
    } else {  // w2 : K=256, Ncol=128
      int m = i - 98304;
      int j = m & 7, t2 = m >> 3;
      int col = t2 & 127, cq = t2 >> 7;
      o2[m] = f2b(w2[((cq >> 2) * 32 + (cq & 3) * 8 + j) * 128 + col]);
    }
  }
  grid.sync();

  // ---- P2: exclusive scan of bh (block 0; 256 threads x 2 entries) ----
  if (b == 0) {
    int v0 = bh[2 * t], v1 = bh[2 * t + 1];
    int pair = v0 + v1;
    smem[t] = pair;
    __syncthreads();
    for (int o = 1; o < 256; o <<= 1) {
      int x = (t >= o) ? smem[t - o] : 0;
      __syncthreads();
      smem[t] += x;
      __syncthreads();
    }
    int ep = smem[t] - pair;
    bbase[2 * t] = ep;
    bcur[2 * t] = ep;
    bbase[2 * t + 1] = ep + v0;
    bcur[2 * t + 1] = ep + v0;
  }
  grid.sync();

  // ---- P3: bin 4096 edges/block into contiguous bucket runs (packed 32-bit) ----
  {
    int* cnt = smem;          // [512]
    int* base = smem + 512;   // [512]
    for (int i = t; i < MAXB; i += 256) cnt[i] = 0;
    __syncthreads();
    int myb[16], myr[16];
    unsigned pk[16];
    const int e0 = b * 4096;
#pragma unroll
    for (int j = 0; j < 16; ++j) {
      int e = e0 + j * 256 + t;
      if (e < E) {
        int d = dst[e];
        pk[j] = ((unsigned)src[e] << 8) | (unsigned)(d & 255);
        int bk = d >> 8;
        myb[j] = bk;
        myr[j] = atomicAdd(&cnt[bk], 1);
      } else {
        myb[j] = -1;
      }
    }
    __syncthreads();
    for (int i = t; i < MAXB; i += 256)
      base[i] = cnt[i] ? atomicAdd(&bcur[i], cnt[i]) : 0;
    __syncthreads();
#pragma unroll
    for (int j = 0; j < 16; ++j)
      if (myb[j] >= 0) binned[(size_t)base[myb[j]] + myr[j]] = pk[j];
  }
  grid.sync();

  // ---- P4: per-bucket fine scatter: deg/offs + csr ----
  if (b < NBuck) {
    int* cnt = smem;         // [256]
    int* cur = smem + 256;   // [256]
    int* sd = smem + 512;    // [256]
    const int node0 = b << 8;
    cnt[t] = 0;
    __syncthreads();
    const int s0 = bbase[b], len = bh[b];
    for (int i = t; i < len; i += 256) atomicAdd(&cnt[binned[(size_t)s0 + i] & 255], 1);
    __syncthreads();
    int v = cnt[t];
    sd[t] = v;
    __syncthreads();
    for (int o = 1; o < 256; o <<= 1) {
      int x = (t >= o) ? sd[t - o] : 0;
      __syncthreads();
      sd[t] += x;
      __syncthreads();
    }
    int excl = sd[t] - v;
    cur[t] = excl;
    int node = node0 + t;
    if (node < N) {
      deg[node] = v;
      offs[node] = s0 + excl;
    }
    __syncthreads();
    for (int i = t; i < len; i += 256) {
      unsigned ed = binned[(size_t)s0 + i];
      int p = atomicAdd(&cur[ed & 255], 1);
      csr[s0 + p] = (int)(ed >> 8);
    }
  }
}

// ------- fused QKV GEMM v5: weights staged in LDS (96 KB), frags via ds_read_b128 --
__global__ __launch_bounds__(512) void gemm_qkv5(const float* __restrict__ A,
                                                 const uint4* __restrict__ wqF,
                                                 const uint4* __restrict__ wkF,
                                                 const uint4* __restrict__ wvF,
                                                 __hip_bfloat16* __restrict__ Q,
                                                 unsigned char* __restrict__ KV8,
                                                 int Nrow) {
  __shared__ short W[3 * 16384];  // 96 KB: Wq | Wk | Wv, frag-ordered
  const int t = threadIdx.x;
  {
    uint4* W4 = (uint4*)W;
    for (int i = t; i < 2048; i += 512) {
      W4[i] = wqF[i];
      W4[i + 2048] = wkF[i];
      W4[i + 4096] = wvF[i];
    }
  }
  __syncthreads();
  const int lane = t & 63;
  const int ct = t >> 6;  // 0..7 (= head)
  const int n = lane & 15, quad = lane >> 4;
  const int fbase = quad * 128 + ct * 16 + n;  // frag idx; +c*512; short off = *8
  const int ntiles = Nrow >> 4;
  const int koff = ct * 32 + ((n >> 3) << 4) + (n & 7);
  int rt = blockIdx.x;
  if (rt >= ntiles) return;
  float4 u[8];
  {
    const float* Ap = A + (size_t)(rt * 16 + n) * 128 + quad * 8;
#pragma unroll
    for (int c = 0; c < 4; ++c) {
      u[2 * c] = *(const float4*)(Ap + c * 32);
      u[2 * c + 1] = *(const float4*)(Ap + c * 32 + 4);
    }
  }
  while (true) {
    const int rtn = rt + gridDim.x;
    const bool more = rtn < ntiles;
    float4 un[8];
    if (more) {  // 1-deep prefetch
      const float* Ap = A + (size_t)(rtn * 16 + n) * 128 + quad * 8;
#pragma unroll
      for (int c = 0; c < 4; ++c) {
        un[2 * c] = *(const float4*)(Ap + c * 32);
        un[2 * c + 1] = *(const float4*)(Ap + c * 32 + 4);
      }
    }
    short8 a[4];
#pragma unroll
    for (int c = 0; c < 4; ++c) a[c] = cvt8(u[2 * c], u[2 * c + 1]);
    float4v aq = {0.f, 0.f, 0.f, 0.f}, ak = aq, av = aq;
#pragma unroll
    for (int c = 0; c < 4; ++c) {
      const int fo = (fbase + c * 512) * 8;
      short8 fq = *(const short8*)&W[fo];
      short8 fk = *(const short8*)&W[16384 + fo];
      short8 fv = *(const short8*)&W[32768 + fo];
      aq = mfma16(a[c], fq, aq);
      ak = mfma16(a[c], fk, ak);
      av = mfma16(a[c], fv, av);
    }
#pragma unroll
    for (int r = 0; r < 4; ++r) {
      int grow = rt * 16 + quad * 4 + r;
      Q[(size_t)grow * 128 + ct * 16 + n] = f2b(aq[r]);
      size_t b = (size_t)grow * 256 + koff;
      KV8[b] = f2fp8(ak[r]);
      KV8[b + 8] = f2fp8(av[r]);
    }
    if (!more) break;
#pragma unroll
    for (int i = 0; i < 8; ++i) u[i] = un[i];
    rt = rtn;
  }
}

// ------ GEMM + bias + residual + LayerNorm, LDS weights, ping-pong tile, 1 bar/iter
template <int K, typename TR, typename TO>
__global__ __launch_bounds__(512) void ln_gemm(const short* __restrict__ A,
                                               const uint4* __restrict__ BF4,
                                               const float* __restrict__ bias,
                                               const TR* __restrict__ resid,
                                               const float* __restrict__ gam,
                                               const float* __restrict__ bet,
                                               TO* __restrict__ Out, int Nrow) {
  __shared__ short W[K * 128];        // K=128: 32 KB, frag-ordered
  __shared__ float tile[2][16][132];  // ping-pong: 1 barrier per iteration
  const int t = threadIdx.x;
  {
    uint4* W4 = (uint4*)W;
    for (int i = t; i < K * 16; i += 512) W4[i] = BF4[i];
  }
  __syncthreads();
  const int lane = t & 63;
  const int ct = t >> 6;
  const int n = lane & 15, quad = lane >> 4;
  const int fbase = quad * 128 + ct * 16 + n;
  float biasv = bias[ct * 16 + n];
  const int row2 = t >> 5, sub = t & 31;
  float ga0 = gam[sub],      ga1 = gam[sub + 32];
  float ga2 = gam[sub + 64], ga3 = gam[sub + 96];
  float be0 = bet[sub],      be1 = bet[sub + 32];
  float be2 = bet[sub + 64], be3 = bet[sub + 96];
  const int ntiles = Nrow >> 4;
  int pp = 0;
  for (int rt = blockIdx.x; rt < ntiles; rt += gridDim.x, pp ^= 1) {
    const short8* Ap = (const short8*)(A + (size_t)(rt * 16 + n) * K + quad * 8);
    short8 a[K / 32];
    float rs[4];
#pragma unroll
    for (int c = 0; c < K / 32; ++c) a[c] = Ap[c * 4];
#pragma unroll
    for (int r = 0; r < 4; ++r)
      rs[r] = ldf(resid, (size_t)(rt * 16 + quad * 4 + r) * 128 + ct * 16 + n);
    float4v acc = {0.f, 0.f, 0.f, 0.f};
#pragma unroll
    for (int c = 0; c < K / 32; ++c) {
      short8 bf = *(const short8*)&W[(fbase + c * 512) * 8];
      acc = mfma16(a[c], bf, acc);
    }
#pragma unroll
    for (int r = 0; r < 4; ++r)
      tile[pp][quad * 4 + r][ct * 16 + n] = acc[r] + biasv + rs[r];
    bar_lds();
    float x0 = tile[pp][row2][sub], x1 = tile[pp][row2][sub + 32];
    float x2 = tile[pp][row2][sub + 64], x3 = tile[pp][row2][sub + 96];
    float s = x0 + x1 + x2 + x3;
    float s2 = x0 * x0 + x1 * x1 + x2 * x2 + x3 * x3;
#pragma unroll
    for (int o = 16; o >= 1; o >>= 1) {
      s += __shfl_xor(s, o);
      s2 += __shfl_xor(s2, o);
    }
    float mean = s * 0.0078125f;
    float var = s2 * 0.0078125f - mean * mean;
    float rstd = rsqrtf(var + 1e-5f);
    size_t base = (size_t)(rt * 16 + row2) * 128;
    stf(Out, base + sub,      (x0 - mean) * rstd * ga0 + be0);
    stf(Out, base + sub + 32, (x1 - mean) * rstd * ga1 + be1);
    stf(Out, base + sub + 64, (x2 - mean) * rstd * ga2 + be2);
    stf(Out, base + sub + 96, (x3 - mean) * rstd * ga3 + be3);
  }
}

// ------ fused FFN: W1+W2 in LDS (128 KB), ping-pong mid, 2 barriers/iter ----------
__global__ __launch_bounds__(512) void ffn_ln(const short* __restrict__ hh,
                                              const uint4* __restrict__ W1F4,
                                              const float* __restrict__ c1,
                                              const uint4* __restrict__ W2F4,
                                              const float* __restrict__ c2,
                                              const float* __restrict__ gam,
                                              const float* __restrict__ bet,
                                              float* __restrict__ Out, int Nrow) {
  __shared__ short W1[32768];         // 64 KB frag-ordered
  __shared__ short W2[32768];         // 64 KB frag-ordered
  __shared__ short mid[2][16][264];   // ping-pong
  __shared__ float tile[16][132];
  const int t = threadIdx.x;
  {
    uint4* a4 = (uint4*)W1;
    uint4* b4 = (uint4*)W2;
    for (int i = t; i < 4096; i += 512) {
      a4[i] = W1F4[i];
      b4[i] = W2F4[i];
    }
  }
  __syncthreads();
  const int lane = t & 63;
  const int wv = t >> 6;
  const int n = lane & 15, quad = lane >> 4;
  float b1v0 = c1[(wv * 2) * 16 + n], b1v1 = c1[(wv * 2 + 1) * 16 + n];
  float b2v = c2[wv * 16 + n];
  const int row2 = t >> 5, sub = t & 31;
  float ga0 = gam[sub],      ga1 = gam[sub + 32];
  float ga2 = gam[sub + 64], ga3 = gam[sub + 96];
  float be0 = bet[sub],      be1 = bet[sub + 32];
  float be2 = bet[sub + 64], be3 = bet[sub + 96];
  const int ntiles = Nrow >> 4;
  const __hip_bfloat16* hb = (const __hip_bfloat16*)hh;
  const int f1b0 = quad * 256 + (wv * 2) * 16 + n;
  const int f1b1 = quad * 256 + (wv * 2 + 1) * 16 + n;
  const int f2b = quad * 128 + wv * 16 + n;
  int rt = blockIdx.x;
  if (rt >= ntiles) return;
  short8 a[4];
  __hip_bfloat16 rs[4];
  {
    const short8* Ap = (const short8*)(hh + (size_t)(rt * 16 + n) * 128 + quad * 8);
#pragma unroll
    for (int c = 0; c < 4; ++c) a[c] = Ap[c * 4];
#pragma unroll
    for (int r = 0; r < 4; ++r)
      rs[r] = hb[(size_t)(rt * 16 + quad * 4 + r) * 128 + wv * 16 + n];
  }
  int mp = 0;
  while (true) {
    const int rtn = rt + gridDim.x;
    const bool more = rtn < ntiles;
    short8 an[4];
    __hip_bfloat16 rsn[4];
    if (more) {  // prefetch survives the relaxed barriers (lgkm-only drain)
      const short8* Ap = (const short8*)(hh + (size_t)(rtn * 16 + n) * 128 + quad * 8);
#pragma unroll
      for (int c = 0; c < 4; ++c) an[c] = Ap[c * 4];
#pragma unroll
      for (int r = 0; r < 4; ++r)
        rsn[r] = hb[(size_t)(rtn * 16 + quad * 4 + r) * 128 + wv * 16 + n];
    }
    // GEMM1: mid = relu(hh @ W1 + c1)
    float4v a10 = {0.f, 0.f, 0.f, 0.f}, a11 = a10;
#pragma unroll
    for (int c = 0; c < 4; ++c) {
      short8 f1a = *(const short8*)&W1[(f1b0 + c * 1024) * 8];
      short8 f1c = *(const short8*)&W1[(f1b1 + c * 1024) * 8];
      a10 = mfma16(a[c], f1a, a10);
      a11 = mfma16(a[c], f1c, a11);
    }
#pragma unroll
    for (int r = 0; r < 4; ++r) {
      mid[mp][quad * 4 + r][(wv * 2) * 16 + n] = (short)f2b_bits(fmaxf(a10[r] + b1v0, 0.f));
      mid[mp][quad * 4 + r][(wv * 2 + 1) * 16 + n] = (short)f2b_bits(fmaxf(a11[r] + b1v1, 0.f));
    }
    bar_lds();
    // GEMM2: acc = mid @ W2 over K=256
    float4v acc = {0.f, 0.f, 0.f, 0.f};
#pragma unroll
    for (int c = 0; c < 8; ++c) {
      short8 am = *(const short8*)&mid[mp][n][quad * 8 + c * 32];
      short8 f2 = *(const short8*)&W2[(f2b + c * 512) * 8];
      acc = mfma16(am, f2, acc);
    }
#pragma unroll
    for (int r = 0; r < 4; ++r)
      tile[quad * 4 + r][wv * 16 + n] = acc[r] + b2v + b2f(rs[r]);
    bar_lds();
    float x0 = tile[row2][sub], x1 = tile[row2][sub + 32];
    float x2 = tile[row2][sub + 64], x3 = tile[row2][sub + 96];
    float s = x0 + x1 + x2 + x3;
    float s2 = x0 * x0 + x1 * x1 + x2 * x2 + x3 * x3;
#pragma unroll
    for (int o = 16; o >= 1; o >>= 1) {
      s += __shfl_xor(s, o);
      s2 += __shfl_xor(s2, o);
    }
    float mean = s * 0.0078125f;
    float var = s2 * 0.0078125f - mean * mean;
    float rstd = rsqrtf(var + 1e-5f);
    size_t base = (size_t)(rt * 16 + row2) * 128;
    Out[base + sub]      = (x0 - mean) * rstd * ga0 + be0;
    Out[base + sub + 32] = (x1 - mean) * rstd * ga1 + be1;
    Out[base + sub + 64] = (x2 - mean) * rstd * ga2 + be2;
    Out[base + sub + 96] = (x3 - mean) * rstd * ga3 + be3;
    if (!more) break;
#pragma unroll
    for (int c = 0; c < 4; ++c) a[c] = an[c];
#pragma unroll
    for (int r = 0; r < 4; ++r) rs[r] = rsn[r];
    rt = rtn;
    mp ^= 1;
  }
}

// ---- attention aggregation v5: fp8 KV gather (256 B/edge), lane = (e4, hd, hf) ----
__global__ __launch_bounds__(256) void attn_agg5(const uint4* __restrict__ Q4,
                                                 const uint4* __restrict__ KV8,
                                                 const int* __restrict__ offs,
                                                 const int* __restrict__ deg,
                                                 const int* __restrict__ csr,
                                                 uint4* __restrict__ AT4, int N) {
  const int lane = threadIdx.x & 63;
  const int wv = threadIdx.x >> 6;
  const int e4 = lane >> 4;        // 0..3  edge slot
  const int hd = (lane >> 1) & 7;  // head
  const int hf = lane & 1;         // half-head: dims hf*8 .. hf*8+7
  const int kvo = hd * 2 + hf;     // uint4 index within a node's 16 x 16B
  for (int node = blockIdx.x * 4 + wv; node < N; node += gridDim.x * 4) {
    uint4 qa = Q4[(size_t)node * 16 + kvo];
    float2v qv[4];
    qv[0] = up2(qa.x); qv[1] = up2(qa.y); qv[2] = up2(qa.z); qv[3] = up2(qa.w);
    float2v acc[4];
#pragma unroll
    for (int d = 0; d < 4; ++d) acc[d] = (float2v){0.f, 0.f};
    float z = 0.f;
    const int st = offs[node], dg = deg[node];
    if (dg > 0) {
      const int dgm1 = dg - 1;
      int s_cur = csr[st + min(e4, dgm1)];
      int s_nxt = (dg > 4) ? csr[st + min(4 + e4, dgm1)] : s_cur;
      uint4 ckv = KV8[(size_t)s_cur * 16 + kvo];
      int i = 0;
      while (true) {
        const bool more = (i + 4) < dg;  // wave-uniform
        uint4 nkv;
        int s_fut = s_nxt;
        if (more) {
          nkv = KV8[(size_t)s_nxt * 16 + kvo];
          s_fut = csr[st + min(i + 8 + e4, dgm1)];
        }
        // ---- compute on current ----
        float2v p2 = cvt2lo(ckv.x) * qv[0];
        p2 += cvt2hi(ckv.x) * qv[1];
        p2 += cvt2lo(ckv.y) * qv[2];
        p2 += cvt2hi(ckv.y) * qv[3];
        float p = p2.x + p2.y;
        p += __shfl_xor(p, 1);  // combine the two half-heads
        float sc = __expf(fminf(fmaxf(p * 0.25f, -5.f), 5.f));
        sc = ((i + e4) < dg) ? sc : 0.f;
        z += sc;
        float2v sv = {sc, sc};
        acc[0] += cvt2lo(ckv.z) * sv;
        acc[1] += cvt2hi(ckv.z) * sv;
        acc[2] += cvt2lo(ckv.w) * sv;
        acc[3] += cvt2hi(ckv.w) * sv;
        if (!more) break;
        ckv = nkv;
        s_nxt = s_fut;
        i += 4;
      }
    }
    // reduce across the 4 edge slots (lane bits 4,5)
#pragma unroll
    for (int m = 16; m <= 32; m <<= 1) {
      z += __shfl_xor(z, m);
#pragma unroll
      for (int d = 0; d < 4; ++d) {
        acc[d].x += __shfl_xor(acc[d].x, m);
        acc[d].y += __shfl_xor(acc[d].y, m);
      }
    }
    if (e4 == 0) {
      float inv = (z > 0.f) ? 1.f / z : 1.f;
      unsigned r[4];
#pragma unroll
      for (int j = 0; j < 4; ++j)
        r[j] = (unsigned)f2b_bits(acc[j].x * inv) |
               ((unsigned)f2b_bits(acc[j].y * inv) << 16);
      AT4[(size_t)node * 16 + kvo] = make_uint4(r[0], r[1], r[2], r[3]);
    }
  }
}

// ---------------- launch ----------------
extern "C" void kernel_launch(void* const* d_in, const int* in_sizes, int n_in,
                              void* d_out, int out_size, void* d_ws, size_t ws_size,
                              hipStream_t stream) {
  const float* h = (const float*)d_in[0];
  const int* src = (const int*)d_in[1];
  const int* dst = (const int*)d_in[2];
  const float* Wq = (const float*)d_in[3];
  const float* Wk = (const float*)d_in[4];
  const float* Wv = (const float*)d_in[5];
  const float* Wo = (const float*)d_in[6];
  const float* bo = (const float*)d_in[7];
  const float* g1 = (const float*)d_in[8];
  const float* b1 = (const float*)d_in[9];
  const float* g2 = (const float*)d_in[10];
  const float* b2 = (const float*)d_in[11];
  const float* W1 = (const float*)d_in[12];
  const float* c1 = (const float*)d_in[13];
  const float* W2 = (const float*)d_in[14];
  const float* c2 = (const float*)d_in[15];

  int N = in_sizes[0] / D;
  int E = in_sizes[1];
  int NBuck = (N + 255) >> 8;

  char* p = (char*)d_ws;
  auto carve = [&](size_t bytes) {
    char* r = p;
    p += (bytes + 255) & ~(size_t)255;
    return r;
  };
  short* ATb = (short*)carve((size_t)N * D * 2);
  short* Qb = (short*)carve((size_t)N * D * 2);        // later hh
  unsigned char* KVb = (unsigned char*)carve((size_t)N * 256);  // fp8 K|V, 256 B/node
  short* wq = (short*)carve(16384 * 2);
  short* wk = (short*)carve(16384 * 2);
  short* wv = (short*)carve(16384 * 2);
  short* wo = (short*)carve(16384 * 2);
  short* w1 = (short*)carve(32768 * 2);
  short* w2 = (short*)carve(32768 * 2);
  int* deg = (int*)carve((size_t)N * 4);
  int* offs = (int*)carve((size_t)N * 4);
  int* bh = (int*)carve(MAXB * 4);
  int* bbase = (int*)carve(MAXB * 4);
  int* bcur = (int*)carve(MAXB * 4);
  unsigned* binned = (unsigned*)carve((size_t)E * 4);
  int* csr = (int*)carve((size_t)E * 4);
  short* hh = Qb;  // alias: Q dead after attn_agg

  __hip_bfloat16* oq = (__hip_bfloat16*)wq;
  __hip_bfloat16* ok = (__hip_bfloat16*)wk;
  __hip_bfloat16* ov = (__hip_bfloat16*)wv;
  __hip_bfloat16* oo = (__hip_bfloat16*)wo;
  __hip_bfloat16* o1 = (__hip_bfloat16*)w1;
  __hip_bfloat16* o2 = (__hip_bfloat16*)w2;

  void* args[] = {(void*)&src, (void*)&dst, (void*)&bh, (void*)&bbase, (void*)&bcur,
                  (void*)&binned, (void*)&deg, (void*)&offs, (void*)&csr,
                  (void*)&Wq, (void*)&Wk, (void*)&Wv, (void*)&Wo, (void*)&W1, (void*)&W2,
                  (void*)&oq, (void*)&ok, (void*)&ov, (void*)&oo, (void*)&o1, (void*)&o2,
                  (void*)&N, (void*)&E, (void*)&NBuck};
  hipLaunchCooperativeKernel((const void*)k_prep, dim3(512), dim3(256), args, 0, stream);

  gemm_qkv5<<<256, 512, 0, stream>>>(h, (const uint4*)wq, (const uint4*)wk,
                                     (const uint4*)wv, (__hip_bfloat16*)Qb, KVb, N);

  attn_agg5<<<(N + 3) >> 2, 256, 0, stream>>>((const uint4*)Qb, (const uint4*)KVb,
                                              offs, deg, csr, (uint4*)ATb, N);

  ln_gemm<128, float, __hip_bfloat16><<<768, 512, 0, stream>>>(
      ATb, (const uint4*)wo, bo, h, g1, b1, (__hip_bfloat16*)hh, N);
  ffn_ln<<<256, 512, 0, stream>>>(hh, (const uint4*)w1, c1, (const uint4*)w2, c2,
                                  g2, b2, (float*)d_out, N);
}

// Round 9
// 392.052 us; speedup vs baseline: 1.5900x; 1.5900x over previous
//
#include <hip/hip_runtime.h>
#include <hip/hip_bf16.h>

#define D 128
#define MAXB 512

typedef __attribute__((ext_vector_type(8))) short short8;
typedef __attribute__((ext_vector_type(4))) float float4v;
typedef __attribute__((ext_vector_type(2))) float float2v;

__device__ __forceinline__ float4v mfma16(short8 a, short8 b, float4v c) {
  return __builtin_amdgcn_mfma_f32_16x16x32_bf16(a, b, c, 0, 0, 0);
}
__device__ __forceinline__ float b2f(__hip_bfloat16 x) { return __bfloat162float(x); }
__device__ __forceinline__ __hip_bfloat16 f2b(float x) { return __float2bfloat16(x); }
__device__ __forceinline__ unsigned short f2b_bits(float x) {
  __hip_bfloat16 h = __float2bfloat16(x);
  return *reinterpret_cast<unsigned short*>(&h);
}

__device__ __forceinline__ float ldf(const float* p, size_t i) { return p[i]; }
__device__ __forceinline__ float ldf(const __hip_bfloat16* p, size_t i) { return b2f(p[i]); }
__device__ __forceinline__ void stf(float* p, size_t i, float v) { p[i] = v; }
__device__ __forceinline__ void stf(__hip_bfloat16* p, size_t i, float v) { p[i] = f2b(v); }

// relaxed workgroup barrier: drain LDS ops only, leave global loads in flight.
__device__ __forceinline__ void bar_lds() {
  asm volatile("s_waitcnt lgkmcnt(0)\n\ts_barrier" ::: "memory");
}

// packed bf16-pair -> float2 (lo, hi)
__device__ __forceinline__ float2v up2(unsigned w) {
  float2v r;
  r.x = __uint_as_float(w << 16);
  r.y = __uint_as_float(w & 0xffff0000u);
  return r;
}
// fp8 e4m3 (OCP on gfx950) encode/decode via the HW cvt pair — self-consistent.
__device__ __forceinline__ unsigned char f2fp8(float x) {
  int r = __builtin_amdgcn_cvt_pk_fp8_f32(x, x, 0, false);
  return (unsigned char)(r & 0xff);
}
__device__ __forceinline__ float2v cvt2lo(unsigned w) {
  return __builtin_amdgcn_cvt_pk_f32_fp8(w, false);
}
__device__ __forceinline__ float2v cvt2hi(unsigned w) {
  return __builtin_amdgcn_cvt_pk_f32_fp8(w, true);
}

__device__ __forceinline__ short8 cvt8(float4 u0, float4 u1) {
  short8 a;
  a[0] = (short)f2b_bits(u0.x); a[1] = (short)f2b_bits(u0.y);
  a[2] = (short)f2b_bits(u0.z); a[3] = (short)f2b_bits(u0.w);
  a[4] = (short)f2b_bits(u1.x); a[5] = (short)f2b_bits(u1.y);
  a[6] = (short)f2b_bits(u1.z); a[7] = (short)f2b_bits(u1.w);
  return a;
}

// ------- bucket histogram (LDS-combined) + weight cast folded in (independent) ----
// frag layout for weights (KxNcol): out[((c*4+quad)*Ncol + col)*8 + j]
//   = W[(c*32 + quad*8 + j)*Ncol + col]  -> one aligned 16-B load per fragment.
__global__ __launch_bounds__(256) void k_bhist_cast(
    const int* __restrict__ dst, int* __restrict__ bh, int E,
    const float* __restrict__ wq, const float* __restrict__ wk,
    const float* __restrict__ wv, const float* __restrict__ wo,
    const float* __restrict__ w1, const float* __restrict__ w2,
    __hip_bfloat16* __restrict__ oq, __hip_bfloat16* __restrict__ ok,
    __hip_bfloat16* __restrict__ ov, __hip_bfloat16* __restrict__ oo,
    __hip_bfloat16* __restrict__ o1, __hip_bfloat16* __restrict__ o2) {
  __shared__ int cnt[MAXB];
  const int t = threadIdx.x;
  const int gid = blockIdx.x * 256 + t;
  for (int i = t; i < MAXB; i += 256) cnt[i] = 0;
  __syncthreads();
  for (int e = gid; e < E; e += gridDim.x * 256) atomicAdd(&cnt[dst[e] >> 8], 1);
  // weight cast: 131072 elements, done by the first 131072 threads
  int i = gid;
  if (i < 65536) {  // wq, wk, wv, wo : K=128, Ncol=128
    int m = i & 16383;
    int which = i >> 14;
    const float* s = (which == 0) ? wq : (which == 1) ? wk : (which == 2) ? wv : wo;
    __hip_bfloat16* o = (which == 0) ? oq : (which == 1) ? ok : (which == 2) ? ov : oo;
    int j = m & 7, t2 = m >> 3;
    int col = t2 & 127, cq = t2 >> 7;
    o[m] = f2b(s[((cq >> 2) * 32 + (cq & 3) * 8 + j) * 128 + col]);
  } else if (i < 98304) {  // w1 : K=128, Ncol=256
    int m = i - 65536;
    int j = m & 7, t2 = m >> 3;
    int col = t2 & 255, cq = t2 >> 8;
    o1[m] = f2b(w1[((cq >> 2) * 32 + (cq & 3) * 8 + j) * 256 + col]);
  } else if (i < 131072) {  // w2 : K=256, Ncol=128
    int m = i - 98304;
    int j = m & 7, t2 = m >> 3;
    int col = t2 & 127, cq = t2 >> 7;
    o2[m] = f2b(w2[((cq >> 2) * 32 + (cq & 3) * 8 + j) * 128 + col]);
  }
  __syncthreads();
  for (int k = t; k < MAXB; k += 256)
    if (cnt[k]) atomicAdd(&bh[k], cnt[k]);
}

__global__ void k_bscan(const int* __restrict__ bh, int* __restrict__ bbase,
                        int* __restrict__ bcur, int B) {
  __shared__ int sd[MAXB];
  int t = threadIdx.x;
  int v = (t < B) ? bh[t] : 0;
  sd[t] = v;
  __syncthreads();
  for (int o = 1; o < MAXB; o <<= 1) {
    int x = (t >= o) ? sd[t - o] : 0;
    __syncthreads();
    sd[t] += x;
    __syncthreads();
  }
  if (t < B) {
    int e = sd[t] - v;
    bbase[t] = e;
    bcur[t] = e;
  }
}

// each block bins 4096 edges into contiguous per-bucket runs (packed 32-bit)
__global__ __launch_bounds__(256) void k_bin(const int* __restrict__ src,
                                             const int* __restrict__ dst,
                                             int* __restrict__ bcur,
                                             unsigned* __restrict__ binned, int E) {
  __shared__ int cnt[MAXB];
  __shared__ int base[MAXB];
  const int t = threadIdx.x;
  const int e0 = blockIdx.x * 4096;
  for (int i = t; i < MAXB; i += 256) cnt[i] = 0;
  __syncthreads();
  int myb[16], myr[16];
  unsigned pk[16];
#pragma unroll
  for (int j = 0; j < 16; ++j) {
    int e = e0 + j * 256 + t;
    if (e < E) {
      int d = dst[e];
      pk[j] = ((unsigned)src[e] << 8) | (unsigned)(d & 255);
      int b = d >> 8;
      myb[j] = b;
      myr[j] = atomicAdd(&cnt[b], 1);
    } else {
      myb[j] = -1;
    }
  }
  __syncthreads();
  for (int i = t; i < MAXB; i += 256)
    base[i] = cnt[i] ? atomicAdd(&bcur[i], cnt[i]) : 0;
  __syncthreads();
#pragma unroll
  for (int j = 0; j < 16; ++j)
    if (myb[j] >= 0) binned[(size_t)base[myb[j]] + myr[j]] = pk[j];
}

// one block per bucket: per-node deg/offs + LDS-local fine scatter into csr
__global__ __launch_bounds__(256) void k_fine(const unsigned* __restrict__ binned,
                                              const int* __restrict__ bh,
                                              const int* __restrict__ bbase,
                                              int* __restrict__ deg,
                                              int* __restrict__ offs,
                                              int* __restrict__ csr, int N) {
  __shared__ int cnt[256];
  __shared__ int cur[256];
  __shared__ int sd[256];
  const int b = blockIdx.x, t = threadIdx.x;
  const int node0 = b << 8;
  cnt[t] = 0;
  __syncthreads();
  const int s0 = bbase[b], len = bh[b];
  for (int i = t; i < len; i += 256) atomicAdd(&cnt[binned[(size_t)s0 + i] & 255], 1);
  __syncthreads();
  int v = cnt[t];
  sd[t] = v;
  __syncthreads();
  for (int o = 1; o < 256; o <<= 1) {
    int x = (t >= o) ? sd[t - o] : 0;
    __syncthreads();
    sd[t] += x;
    __syncthreads();
  }
  int excl = sd[t] - v;
  cur[t] = excl;
  int node = node0 + t;
  if (node < N) {
    deg[node] = v;
    offs[node] = s0 + excl;
  }
  __syncthreads();
  for (int i = t; i < len; i += 256) {
    unsigned ed = binned[(size_t)s0 + i];
    int p = atomicAdd(&cur[ed & 255], 1);
    csr[s0 + p] = (int)(ed >> 8);
  }
}

// ------- fused QKV GEMM v6: 1024 threads (16 waves/CU), weights in LDS (96 KB) ----
// Two half-blocks of 512 threads each process independent tile streams.
__global__ __launch_bounds__(1024) void gemm_qkv6(const float* __restrict__ A,
                                                  const uint4* __restrict__ wqF,
                                                  const uint4* __restrict__ wkF,
                                                  const uint4* __restrict__ wvF,
                                                  __hip_bfloat16* __restrict__ Q,
                                                  unsigned char* __restrict__ KV8,
                                                  int Nrow) {
  __shared__ short W[3 * 16384];  // 96 KB: Wq | Wk | Wv, frag-ordered
  const int t = threadIdx.x;
  {
    uint4* W4 = (uint4*)W;
    for (int i = t; i < 2048; i += 1024) {
      W4[i] = wqF[i];
      W4[i + 2048] = wkF[i];
      W4[i + 4096] = wvF[i];
    }
  }
  __syncthreads();
  const int half = t >> 9;         // 0..1 — independent tile stream
  const int th = t & 511;
  const int lane = th & 63;
  const int ct = th >> 6;          // 0..7 (= head)
  const int n = lane & 15, quad = lane >> 4;
  const int fbase = quad * 128 + ct * 16 + n;
  const int ntiles = Nrow >> 4;
  const int koff = ct * 32 + ((n >> 3) << 4) + (n & 7);
  const int step = gridDim.x * 2;
  int rt = blockIdx.x * 2 + half;
  if (rt >= ntiles) return;
  float4 u[8];
  {
    const float* Ap = A + (size_t)(rt * 16 + n) * 128 + quad * 8;
#pragma unroll
    for (int c = 0; c < 4; ++c) {
      u[2 * c] = *(const float4*)(Ap + c * 32);
      u[2 * c + 1] = *(const float4*)(Ap + c * 32 + 4);
    }
  }
  while (true) {
    const int rtn = rt + step;
    const bool more = rtn < ntiles;
    float4 un[8];
    if (more) {  // 1-deep prefetch
      const float* Ap = A + (size_t)(rtn * 16 + n) * 128 + quad * 8;
#pragma unroll
      for (int c = 0; c < 4; ++c) {
        un[2 * c] = *(const float4*)(Ap + c * 32);
        un[2 * c + 1] = *(const float4*)(Ap + c * 32 + 4);
      }
    }
    short8 a[4];
#pragma unroll
    for (int c = 0; c < 4; ++c) a[c] = cvt8(u[2 * c], u[2 * c + 1]);
    float4v aq = {0.f, 0.f, 0.f, 0.f}, ak = aq, av = aq;
#pragma unroll
    for (int c = 0; c < 4; ++c) {
      const int fo = (fbase + c * 512) * 8;
      short8 fq = *(const short8*)&W[fo];
      short8 fk = *(const short8*)&W[16384 + fo];
      short8 fv = *(const short8*)&W[32768 + fo];
      aq = mfma16(a[c], fq, aq);
      ak = mfma16(a[c], fk, ak);
      av = mfma16(a[c], fv, av);
    }
#pragma unroll
    for (int r = 0; r < 4; ++r) {
      int grow = rt * 16 + quad * 4 + r;
      Q[(size_t)grow * 128 + ct * 16 + n] = f2b(aq[r]);
      size_t b = (size_t)grow * 256 + koff;
      KV8[b] = f2fp8(ak[r]);
      KV8[b + 8] = f2fp8(av[r]);
    }
    if (!more) break;
#pragma unroll
    for (int i = 0; i < 8; ++i) u[i] = un[i];
    rt = rtn;
  }
}

// ------ GEMM + bias + residual + LayerNorm, LDS weights, ping-pong tile, 1 bar/iter
template <int K, typename TR, typename TO>
__global__ __launch_bounds__(512) void ln_gemm(const short* __restrict__ A,
                                               const uint4* __restrict__ BF4,
                                               const float* __restrict__ bias,
                                               const TR* __restrict__ resid,
                                               const float* __restrict__ gam,
                                               const float* __restrict__ bet,
                                               TO* __restrict__ Out, int Nrow) {
  __shared__ short W[K * 128];        // K=128: 32 KB, frag-ordered
  __shared__ float tile[2][16][132];  // ping-pong: 1 barrier per iteration
  const int t = threadIdx.x;
  {
    uint4* W4 = (uint4*)W;
    for (int i = t; i < K * 16; i += 512) W4[i] = BF4[i];
  }
  __syncthreads();
  const int lane = t & 63;
  const int ct = t >> 6;
  const int n = lane & 15, quad = lane >> 4;
  const int fbase = quad * 128 + ct * 16 + n;
  float biasv = bias[ct * 16 + n];
  const int row2 = t >> 5, sub = t & 31;
  float ga0 = gam[sub],      ga1 = gam[sub + 32];
  float ga2 = gam[sub + 64], ga3 = gam[sub + 96];
  float be0 = bet[sub],      be1 = bet[sub + 32];
  float be2 = bet[sub + 64], be3 = bet[sub + 96];
  const int ntiles = Nrow >> 4;
  int pp = 0;
  for (int rt = blockIdx.x; rt < ntiles; rt += gridDim.x, pp ^= 1) {
    const short8* Ap = (const short8*)(A + (size_t)(rt * 16 + n) * K + quad * 8);
    short8 a[K / 32];
    float rs[4];
#pragma unroll
    for (int c = 0; c < K / 32; ++c) a[c] = Ap[c * 4];
#pragma unroll
    for (int r = 0; r < 4; ++r)
      rs[r] = ldf(resid, (size_t)(rt * 16 + quad * 4 + r) * 128 + ct * 16 + n);
    float4v acc = {0.f, 0.f, 0.f, 0.f};
#pragma unroll
    for (int c = 0; c < K / 32; ++c) {
      short8 bf = *(const short8*)&W[(fbase + c * 512) * 8];
      acc = mfma16(a[c], bf, acc);
    }
#pragma unroll
    for (int r = 0; r < 4; ++r)
      tile[pp][quad * 4 + r][ct * 16 + n] = acc[r] + biasv + rs[r];
    bar_lds();
    float x0 = tile[pp][row2][sub], x1 = tile[pp][row2][sub + 32];
    float x2 = tile[pp][row2][sub + 64], x3 = tile[pp][row2][sub + 96];
    float s = x0 + x1 + x2 + x3;
    float s2 = x0 * x0 + x1 * x1 + x2 * x2 + x3 * x3;
#pragma unroll
    for (int o = 16; o >= 1; o >>= 1) {
      s += __shfl_xor(s, o);
      s2 += __shfl_xor(s2, o);
    }
    float mean = s * 0.0078125f;
    float var = s2 * 0.0078125f - mean * mean;
    float rstd = rsqrtf(var + 1e-5f);
    size_t base = (size_t)(rt * 16 + row2) * 128;
    stf(Out, base + sub,      (x0 - mean) * rstd * ga0 + be0);
    stf(Out, base + sub + 32, (x1 - mean) * rstd * ga1 + be1);
    stf(Out, base + sub + 64, (x2 - mean) * rstd * ga2 + be2);
    stf(Out, base + sub + 96, (x3 - mean) * rstd * ga3 + be3);
  }
}

// ------ fused FFN: W1+W2 in LDS (128 KB), ping-pong mid, 2 barriers/iter ----------
__global__ __launch_bounds__(512) void ffn_ln(const short* __restrict__ hh,
                                              const uint4* __restrict__ W1F4,
                                              const float* __restrict__ c1,
                                              const uint4* __restrict__ W2F4,
                                              const float* __restrict__ c2,
                                              const float* __restrict__ gam,
                                              const float* __restrict__ bet,
                                              float* __restrict__ Out, int Nrow) {
  __shared__ short W1[32768];         // 64 KB frag-ordered
  __shared__ short W2[32768];         // 64 KB frag-ordered
  __shared__ short mid[2][16][264];   // ping-pong
  __shared__ float tile[16][132];
  const int t = threadIdx.x;
  {
    uint4* a4 = (uint4*)W1;
    uint4* b4 = (uint4*)W2;
    for (int i = t; i < 4096; i += 512) {
      a4[i] = W1F4[i];
      b4[i] = W2F4[i];
    }
  }
  __syncthreads();
  const int lane = t & 63;
  const int wv = t >> 6;
  const int n = lane & 15, quad = lane >> 4;
  float b1v0 = c1[(wv * 2) * 16 + n], b1v1 = c1[(wv * 2 + 1) * 16 + n];
  float b2v = c2[wv * 16 + n];
  const int row2 = t >> 5, sub = t & 31;
  float ga0 = gam[sub],      ga1 = gam[sub + 32];
  float ga2 = gam[sub + 64], ga3 = gam[sub + 96];
  float be0 = bet[sub],      be1 = bet[sub + 32];
  float be2 = bet[sub + 64], be3 = bet[sub + 96];
  const int ntiles = Nrow >> 4;
  const __hip_bfloat16* hb = (const __hip_bfloat16*)hh;
  const int f1b0 = quad * 256 + (wv * 2) * 16 + n;
  const int f1b1 = quad * 256 + (wv * 2 + 1) * 16 + n;
  const int f2b = quad * 128 + wv * 16 + n;
  int rt = blockIdx.x;
  if (rt >= ntiles) return;
  short8 a[4];
  __hip_bfloat16 rs[4];
  {
    const short8* Ap = (const short8*)(hh + (size_t)(rt * 16 + n) * 128 + quad * 8);
#pragma unroll
    for (int c = 0; c < 4; ++c) a[c] = Ap[c * 4];
#pragma unroll
    for (int r = 0; r < 4; ++r)
      rs[r] = hb[(size_t)(rt * 16 + quad * 4 + r) * 128 + wv * 16 + n];
  }
  int mp = 0;
  while (true) {
    const int rtn = rt + gridDim.x;
    const bool more = rtn < ntiles;
    short8 an[4];
    __hip_bfloat16 rsn[4];
    if (more) {  // prefetch survives the relaxed barriers (lgkm-only drain)
      const short8* Ap = (const short8*)(hh + (size_t)(rtn * 16 + n) * 128 + quad * 8);
#pragma unroll
      for (int c = 0; c < 4; ++c) an[c] = Ap[c * 4];
#pragma unroll
      for (int r = 0; r < 4; ++r)
        rsn[r] = hb[(size_t)(rtn * 16 + quad * 4 + r) * 128 + wv * 16 + n];
    }
    // GEMM1: mid = relu(hh @ W1 + c1)
    float4v a10 = {0.f, 0.f, 0.f, 0.f}, a11 = a10;
#pragma unroll
    for (int c = 0; c < 4; ++c) {
      short8 f1a = *(const short8*)&W1[(f1b0 + c * 1024) * 8];
      short8 f1c = *(const short8*)&W1[(f1b1 + c * 1024) * 8];
      a10 = mfma16(a[c], f1a, a10);
      a11 = mfma16(a[c], f1c, a11);
    }
#pragma unroll
    for (int r = 0; r < 4; ++r) {
      mid[mp][quad * 4 + r][(wv * 2) * 16 + n] = (short)f2b_bits(fmaxf(a10[r] + b1v0, 0.f));
      mid[mp][quad * 4 + r][(wv * 2 + 1) * 16 + n] = (short)f2b_bits(fmaxf(a11[r] + b1v1, 0.f));
    }
    bar_lds();
    // GEMM2: acc = mid @ W2 over K=256
    float4v acc = {0.f, 0.f, 0.f, 0.f};
#pragma unroll
    for (int c = 0; c < 8; ++c) {
      short8 am = *(const short8*)&mid[mp][n][quad * 8 + c * 32];
      short8 f2 = *(const short8*)&W2[(f2b + c * 512) * 8];
      acc = mfma16(am, f2, acc);
    }
#pragma unroll
    for (int r = 0; r < 4; ++r)
      tile[quad * 4 + r][wv * 16 + n] = acc[r] + b2v + b2f(rs[r]);
    bar_lds();
    float x0 = tile[row2][sub], x1 = tile[row2][sub + 32];
    float x2 = tile[row2][sub + 64], x3 = tile[row2][sub + 96];
    float s = x0 + x1 + x2 + x3;
    float s2 = x0 * x0 + x1 * x1 + x2 * x2 + x3 * x3;
#pragma unroll
    for (int o = 16; o >= 1; o >>= 1) {
      s += __shfl_xor(s, o);
      s2 += __shfl_xor(s2, o);
    }
    float mean = s * 0.0078125f;
    float var = s2 * 0.0078125f - mean * mean;
    float rstd = rsqrtf(var + 1e-5f);
    size_t base = (size_t)(rt * 16 + row2) * 128;
    Out[base + sub]      = (x0 - mean) * rstd * ga0 + be0;
    Out[base + sub + 32] = (x1 - mean) * rstd * ga1 + be1;
    Out[base + sub + 64] = (x2 - mean) * rstd * ga2 + be2;
    Out[base + sub + 96] = (x3 - mean) * rstd * ga3 + be3;
    if (!more) break;
#pragma unroll
    for (int c = 0; c < 4; ++c) a[c] = an[c];
#pragma unroll
    for (int r = 0; r < 4; ++r) rs[r] = rsn[r];
    rt = rtn;
    mp ^= 1;
  }
}

// ---- attention aggregation v5: fp8 KV gather (256 B/edge), lane = (e4, hd, hf) ----
__global__ __launch_bounds__(256) void attn_agg5(const uint4* __restrict__ Q4,
                                                 const uint4* __restrict__ KV8,
                                                 const int* __restrict__ offs,
                                                 const int* __restrict__ deg,
                                                 const int* __restrict__ csr,
                                                 uint4* __restrict__ AT4, int N) {
  const int lane = threadIdx.x & 63;
  const int wv = threadIdx.x >> 6;
  const int e4 = lane >> 4;        // 0..3  edge slot
  const int hd = (lane >> 1) & 7;  // head
  const int hf = lane & 1;         // half-head: dims hf*8 .. hf*8+7
  const int kvo = hd * 2 + hf;     // uint4 index within a node's 16 x 16B
  for (int node = blockIdx.x * 4 + wv; node < N; node += gridDim.x * 4) {
    uint4 qa = Q4[(size_t)node * 16 + kvo];
    float2v qv[4];
    qv[0] = up2(qa.x); qv[1] = up2(qa.y); qv[2] = up2(qa.z); qv[3] = up2(qa.w);
    float2v acc[4];
#pragma unroll
    for (int d = 0; d < 4; ++d) acc[d] = (float2v){0.f, 0.f};
    float z = 0.f;
    const int st = offs[node], dg = deg[node];
    if (dg > 0) {
      const int dgm1 = dg - 1;
      int s_cur = csr[st + min(e4, dgm1)];
      int s_nxt = (dg > 4) ? csr[st + min(4 + e4, dgm1)] : s_cur;
      uint4 ckv = KV8[(size_t)s_cur * 16 + kvo];
      int i = 0;
      while (true) {
        const bool more = (i + 4) < dg;  // wave-uniform
        uint4 nkv;
        int s_fut = s_nxt;
        if (more) {
          nkv = KV8[(size_t)s_nxt * 16 + kvo];
          s_fut = csr[st + min(i + 8 + e4, dgm1)];
        }
        // ---- compute on current ----
        float2v p2 = cvt2lo(ckv.x) * qv[0];
        p2 += cvt2hi(ckv.x) * qv[1];
        p2 += cvt2lo(ckv.y) * qv[2];
        p2 += cvt2hi(ckv.y) * qv[3];
        float p = p2.x + p2.y;
        p += __shfl_xor(p, 1);  // combine the two half-heads
        float sc = __expf(fminf(fmaxf(p * 0.25f, -5.f), 5.f));
        sc = ((i + e4) < dg) ? sc : 0.f;
        z += sc;
        float2v sv = {sc, sc};
        acc[0] += cvt2lo(ckv.z) * sv;
        acc[1] += cvt2hi(ckv.z) * sv;
        acc[2] += cvt2lo(ckv.w) * sv;
        acc[3] += cvt2hi(ckv.w) * sv;
        if (!more) break;
        ckv = nkv;
        s_nxt = s_fut;
        i += 4;
      }
    }
    // reduce across the 4 edge slots (lane bits 4,5)
#pragma unroll
    for (int m = 16; m <= 32; m <<= 1) {
      z += __shfl_xor(z, m);
#pragma unroll
      for (int d = 0; d < 4; ++d) {
        acc[d].x += __shfl_xor(acc[d].x, m);
        acc[d].y += __shfl_xor(acc[d].y, m);
      }
    }
    if (e4 == 0) {
      float inv = (z > 0.f) ? 1.f / z : 1.f;
      unsigned r[4];
#pragma unroll
      for (int j = 0; j < 4; ++j)
        r[j] = (unsigned)f2b_bits(acc[j].x * inv) |
               ((unsigned)f2b_bits(acc[j].y * inv) << 16);
      AT4[(size_t)node * 16 + kvo] = make_uint4(r[0], r[1], r[2], r[3]);
    }
  }
}

// ---------------- launch ----------------
extern "C" void kernel_launch(void* const* d_in, const int* in_sizes, int n_in,
                              void* d_out, int out_size, void* d_ws, size_t ws_size,
                              hipStream_t stream) {
  const float* h = (const float*)d_in[0];
  const int* src = (const int*)d_in[1];
  const int* dst = (const int*)d_in[2];
  const float* Wq = (const float*)d_in[3];
  const float* Wk = (const float*)d_in[4];
  const float* Wv = (const float*)d_in[5];
  const float* Wo = (const float*)d_in[6];
  const float* bo = (const float*)d_in[7];
  const float* g1 = (const float*)d_in[8];
  const float* b1 = (const float*)d_in[9];
  const float* g2 = (const float*)d_in[10];
  const float* b2 = (const float*)d_in[11];
  const float* W1 = (const float*)d_in[12];
  const float* c1 = (const float*)d_in[13];
  const float* W2 = (const float*)d_in[14];
  const float* c2 = (const float*)d_in[15];

  const int N = in_sizes[0] / D;
  const int E = in_sizes[1];
  const int B = (N + 255) >> 8;

  char* p = (char*)d_ws;
  auto carve = [&](size_t bytes) {
    char* r = p;
    p += (bytes + 255) & ~(size_t)255;
    return r;
  };
  short* ATb = (short*)carve((size_t)N * D * 2);
  short* Qb = (short*)carve((size_t)N * D * 2);        // later hh
  unsigned char* KVb = (unsigned char*)carve((size_t)N * 256);  // fp8 K|V, 256 B/node
  short* wq = (short*)carve(16384 * 2);
  short* wk = (short*)carve(16384 * 2);
  short* wv = (short*)carve(16384 * 2);
  short* wo = (short*)carve(16384 * 2);
  short* w1 = (short*)carve(32768 * 2);
  short* w2 = (short*)carve(32768 * 2);
  int* deg = (int*)carve((size_t)N * 4);
  int* offs = (int*)carve((size_t)N * 4);
  int* bh = (int*)carve(MAXB * 4);
  int* bbase = (int*)carve(MAXB * 4);
  int* bcur = (int*)carve(MAXB * 4);
  unsigned* binned = (unsigned*)carve((size_t)E * 4);
  int* csr = (int*)carve((size_t)E * 4);
  short* hh = Qb;  // alias: Q dead after attn_agg

  hipMemsetAsync(bh, 0, MAXB * 4, stream);
  k_bhist_cast<<<1024, 256, 0, stream>>>(
      dst, bh, E, Wq, Wk, Wv, Wo, W1, W2,
      (__hip_bfloat16*)wq, (__hip_bfloat16*)wk, (__hip_bfloat16*)wv,
      (__hip_bfloat16*)wo, (__hip_bfloat16*)w1, (__hip_bfloat16*)w2);
  k_bscan<<<1, MAXB, 0, stream>>>(bh, bbase, bcur, B);
  k_bin<<<(E + 4095) / 4096, 256, 0, stream>>>(src, dst, bcur, binned, E);
  k_fine<<<B, 256, 0, stream>>>(binned, bh, bbase, deg, offs, csr, N);

  gemm_qkv6<<<256, 1024, 0, stream>>>(h, (const uint4*)wq, (const uint4*)wk,
                                      (const uint4*)wv, (__hip_bfloat16*)Qb, KVb, N);

  attn_agg5<<<(N + 3) >> 2, 256, 0, stream>>>((const uint4*)Qb, (const uint4*)KVb,
                                              offs, deg, csr, (uint4*)ATb, N);

  ln_gemm<128, float, __hip_bfloat16><<<768, 512, 0, stream>>>(
      ATb, (const uint4*)wo, bo, h, g1, b1, (__hip_bfloat16*)hh, N);
  ffn_ln<<<256, 512, 0, stream>>>(hh, (const uint4*)w1, c1, (const uint4*)w2, c2,
                                  g2, b2, (float*)d_out, N);
}